// Round 1
// baseline (542.832 us; speedup 1.0000x reference)
//
#include <hip/hip_runtime.h>
#include <math.h>

// Problem constants (fixed by the reference harness)
#define BATCH 4
#define SEQ   4096
#define DIM   1024
#define TOPK  64          // min(GLOBAL_BUDGET=64, int(4096*0.05)=204)
#define RSTRIDE 10        // max(1, 4096 // 409)
#define RBUDGET 409       // min(4096, int(4096*0.1))
#define LOCALW  128

// d_ws layout:
//   [0, BATCH*SEQ) floats              : scores
//   then BATCH*SEQ bytes               : flags (bit0=valid, bit1=global, bit2=random)
//   then 4 uints                       : per-batch connection counters
#define WS_SCORES_OFF 0
#define WS_FLAGS_OFF  (BATCH * SEQ * sizeof(float))
#define WS_COUNTS_OFF (WS_FLAGS_OFF + BATCH * SEQ)

__global__ void init_counts_kernel(unsigned int* counts) {
    if (threadIdx.x < BATCH) counts[threadIdx.x] = 0u;
}

// One wave (64 lanes) per (b,s) row: score = dot(hidden[b,s,:], W)
__global__ void scores_kernel(const float* __restrict__ hs,
                              const int* __restrict__ amask,
                              const float* __restrict__ W,
                              float* __restrict__ scores) {
    int row  = blockIdx.x * 4 + (threadIdx.x >> 6);   // 4 waves / block
    int lane = threadIdx.x & 63;
    const float4* h4 = (const float4*)(hs + (size_t)row * DIM);
    const float4* w4 = (const float4*)W;
    float acc = 0.0f;
#pragma unroll
    for (int k = 0; k < DIM / 4 / 64; ++k) {          // 4 iterations
        float4 h = h4[lane + 64 * k];
        float4 w = w4[lane + 64 * k];
        acc += h.x * w.x + h.y * w.y + h.z * w.z + h.w * w.w;
    }
#pragma unroll
    for (int off = 32; off; off >>= 1) acc += __shfl_down(acc, off, 64);
    if (lane == 0)
        scores[row] = amask[row] ? acc : -INFINITY;
}

// One block per batch: iterative top-64 argmax (ties -> lowest index, matching
// jax.lax.top_k), then emit combined flag byte per (b, j).
__global__ void topk_flags_kernel(const float* __restrict__ scores,
                                  const int* __restrict__ amask,
                                  unsigned char* __restrict__ flags) {
    __shared__ float sv[SEQ];
    __shared__ unsigned char gsel[SEQ];
    __shared__ float rv[256];
    __shared__ int   ri[256];
    int b = blockIdx.x, t = threadIdx.x;
    for (int k = t; k < SEQ; k += 256) { sv[k] = scores[b * SEQ + k]; gsel[k] = 0; }
    __syncthreads();

    for (int iter = 0; iter < TOPK; ++iter) {
        // per-thread scan: idx = t + 256*k ascending, strict > keeps lowest idx
        float best = sv[t];
        int   bi   = t;
#pragma unroll
        for (int k = 1; k < SEQ / 256; ++k) {
            int idx = t + 256 * k;
            float v = sv[idx];
            if (v > best) { best = v; bi = idx; }
        }
        rv[t] = best; ri[t] = bi;
        __syncthreads();
        for (int s2 = 128; s2; s2 >>= 1) {
            if (t < s2) {
                float ov = rv[t + s2]; int oi = ri[t + s2];
                if (ov > rv[t] || (ov == rv[t] && oi < ri[t])) { rv[t] = ov; ri[t] = oi; }
            }
            __syncthreads();
        }
        if (t == 0) { int w = ri[0]; gsel[w] = 1; sv[w] = -INFINITY; }
        __syncthreads();
    }

    for (int k = t; k < SEQ; k += 256) {
        int valid = (amask[b * SEQ + k] != 0) ? 1 : 0;
        int g = gsel[k];
        int r = ((k % RSTRIDE) == 0 && (k / RSTRIDE) < RBUDGET) ? 1 : 0;
        flags[b * SEQ + k] = (unsigned char)(valid | (g << 1) | (r << 2));
    }
}

// One block per output row (b,i): write 4096 floats as float4, count ones.
__global__ void mask_kernel(const unsigned char* __restrict__ flags,
                            float* __restrict__ out,
                            unsigned int* __restrict__ counts) {
    int row = blockIdx.x;            // b*SEQ + i
    int b = row >> 12;
    int i = row & (SEQ - 1);
    int t = threadIdx.x;

    unsigned char fi = flags[row];
    int validI = fi & 1;
    int hotI   = (fi >> 1) & 1 | (fi >> 2) & 1;   // gI | rI

    float4* out4 = (float4*)(out + (size_t)row * SEQ);
    const uchar4* f4 = (const uchar4*)(flags + b * SEQ);

    int cnt = 0;
#pragma unroll
    for (int k = 0; k < 4; ++k) {
        int j4 = t + 256 * k;        // float4 index within row
        uchar4 fj = f4[j4];
        unsigned char fja[4] = {fj.x, fj.y, fj.z, fj.w};
        int j0 = j4 * 4;
        float4 v;
        float* vp = (float*)&v;
#pragma unroll
        for (int e = 0; e < 4; ++e) {
            int j = j0 + e;
            unsigned char f = fja[e];
            int keep = (j <= i) & validI & (f & 1);
            int hot  = ((i - j) < LOCALW) | hotI | ((f & 6) != 0);
            int one  = keep & hot;
            vp[e] = one ? 1.0f : 0.0f;
            cnt += one;
        }
        out4[j4] = v;
    }

    // block-reduce cnt -> one atomic per block
#pragma unroll
    for (int off = 32; off; off >>= 1) cnt += __shfl_down(cnt, off, 64);
    __shared__ int wsum[4];
    int wid = t >> 6;
    if ((t & 63) == 0) wsum[wid] = cnt;
    __syncthreads();
    if (t == 0)
        atomicAdd(counts + b, (unsigned int)(wsum[0] + wsum[1] + wsum[2] + wsum[3]));
}

// selected (all True by construction: local.any(axis=0) is all-True) + efficiency
__global__ void finalize_kernel(const unsigned int* __restrict__ counts,
                                float* __restrict__ out_selected,
                                float* __restrict__ out_eff) {
    int idx = blockIdx.x * 256 + threadIdx.x;
    if (idx < BATCH * SEQ) out_selected[idx] = 1.0f;
    if (idx < BATCH)
        out_eff[idx] = (float)counts[idx] * (1.0f / ((float)SEQ * (float)SEQ));
}

extern "C" void kernel_launch(void* const* d_in, const int* in_sizes, int n_in,
                              void* d_out, int out_size, void* d_ws, size_t ws_size,
                              hipStream_t stream) {
    const float* hs    = (const float*)d_in[0];   // [B,S,D] f32
    const int*   amask = (const int*)d_in[1];     // [B,S] i32
    const float* W     = (const float*)d_in[2];   // [1,D] f32

    char* ws = (char*)d_ws;
    float*         scores = (float*)(ws + WS_SCORES_OFF);
    unsigned char* flags  = (unsigned char*)(ws + WS_FLAGS_OFF);
    unsigned int*  counts = (unsigned int*)(ws + WS_COUNTS_OFF);

    float* out_sparse   = (float*)d_out;                         // B*S*S
    float* out_selected = out_sparse + (size_t)BATCH * SEQ * SEQ; // B*S
    float* out_eff      = out_selected + BATCH * SEQ;             // B

    init_counts_kernel<<<1, 64, 0, stream>>>(counts);
    scores_kernel<<<BATCH * SEQ / 4, 256, 0, stream>>>(hs, amask, W, scores);
    topk_flags_kernel<<<BATCH, 256, 0, stream>>>(scores, amask, flags);
    mask_kernel<<<BATCH * SEQ, 256, 0, stream>>>(flags, out_sparse, counts);
    finalize_kernel<<<(BATCH * SEQ + 255) / 256, 256, 0, stream>>>(
        counts, out_selected, out_eff);
}

// Round 3
// 336.308 us; speedup vs baseline: 1.6141x; 1.6141x over previous
//
#include <hip/hip_runtime.h>
#include <math.h>

// Problem constants (fixed by the reference harness)
#define BATCH 4
#define SEQ   4096
#define DIM   1024
#define TOPK  64          // min(GLOBAL_BUDGET=64, int(4096*0.05)=204)
#define RSTRIDE 10        // max(1, 4096 // 409)
#define RBUDGET 409       // min(4096, int(4096*0.1))
#define LOCALW  128

typedef float nfloat4 __attribute__((ext_vector_type(4)));  // native vec for nontemporal store

// d_ws layout:
//   [0, BATCH*SEQ) floats : scores
//   then BATCH*SEQ bytes  : flags (bit0=valid, bit1=global, bit2=random)
#define WS_SCORES_OFF 0
#define WS_FLAGS_OFF  (BATCH * SEQ * sizeof(float))

// One wave (64 lanes) per (b,s) row: score = dot(hidden[b,s,:], W)
__global__ void scores_kernel(const float* __restrict__ hs,
                              const int* __restrict__ amask,
                              const float* __restrict__ W,
                              float* __restrict__ scores) {
    int row  = blockIdx.x * 4 + (threadIdx.x >> 6);   // 4 waves / block
    int lane = threadIdx.x & 63;
    const float4* h4 = (const float4*)(hs + (size_t)row * DIM);
    const float4* w4 = (const float4*)W;
    float acc = 0.0f;
#pragma unroll
    for (int k = 0; k < DIM / 4 / 64; ++k) {          // 4 iterations
        float4 h = h4[lane + 64 * k];
        float4 w = w4[lane + 64 * k];
        acc += h.x * w.x + h.y * w.y + h.z * w.z + h.w * w.w;
    }
#pragma unroll
    for (int off = 32; off; off >>= 1) acc += __shfl_down(acc, off, 64);
    if (lane == 0)
        scores[row] = amask[row] ? acc : -INFINITY;
}

// One block per batch: exact top-64 via 4-pass byte radix select.
// Selection set = {u > T} ∪ {lowest-index elements with u == T}, identical to
// jax.lax.top_k (ties -> lowest index). Then emit combined flag byte per (b,j).
__global__ void topk_flags_kernel(const float* __restrict__ scores,
                                  const int* __restrict__ amask,
                                  unsigned char* __restrict__ flags) {
    __shared__ unsigned int su[SEQ];          // orderable keys
    __shared__ unsigned char gsel[SEQ];
    __shared__ unsigned int hist[257];
    __shared__ unsigned int sufA[257];
    __shared__ unsigned int sufB[257];
    __shared__ unsigned int bcast[2];

    int b = blockIdx.x, t = threadIdx.x;

    // coalesced load + monotonic float->uint map
    for (int k = t; k < SEQ; k += 256) {
        float s = scores[b * SEQ + k];
        unsigned int x = __float_as_uint(s);
        su[k] = (x & 0x80000000u) ? ~x : (x | 0x80000000u);
        gsel[k] = 0;
    }
    __syncthreads();

    unsigned int prefixVal = 0;
    unsigned int remaining = TOPK;
#pragma unroll
    for (int pass = 0; pass < 4; ++pass) {
        int shift = 24 - 8 * pass;
        unsigned int highmask = (pass == 0) ? 0u : (0xFFFFFFFFu << (shift + 8));

        hist[t] = 0;
        if (t == 0) hist[256] = 0;
        __syncthreads();

        // histogram of current byte over candidates (high bits == prefixVal)
#pragma unroll
        for (int e = 0; e < SEQ / 256; ++e) {
            unsigned int u = su[t * (SEQ / 256) + e];
            if ((u & highmask) == prefixVal)
                atomicAdd(&hist[(u >> shift) & 0xFFu], 1u);
        }
        __syncthreads();

        // suffix scan: suf[v] = sum_{w >= v} hist[w]
        sufA[t] = hist[t];
        if (t == 0) sufA[256] = 0;
        __syncthreads();
        unsigned int* src = sufA;
        unsigned int* dst = sufB;
        for (int d = 1; d < 256; d <<= 1) {
            unsigned int v = src[t] + ((t + d < 256) ? src[t + d] : 0u);
            dst[t] = v;
            if (t == 0) dst[256] = 0;
            __syncthreads();
            unsigned int* tmp = src; src = dst; dst = tmp;
        }
        // unique v with suf[v] >= remaining > suf[v+1]
        if (src[t] >= remaining && src[t + 1] < remaining) {
            bcast[0] = (unsigned int)t;
            bcast[1] = remaining - src[t + 1];
        }
        __syncthreads();
        prefixVal |= (bcast[0] << shift);
        remaining = bcast[1];
        __syncthreads();
    }

    // stable selection of `remaining` lowest-index elements equal to T
    unsigned int T = prefixVal;
    unsigned int myeq = 0;
#pragma unroll
    for (int e = 0; e < SEQ / 256; ++e)
        if (su[t * (SEQ / 256) + e] == T) myeq++;
    sufA[t] = myeq;
    __syncthreads();
    {
        unsigned int* src = sufA;
        unsigned int* dst = sufB;
        for (int d = 1; d < 256; d <<= 1) {
            unsigned int v = src[t] + ((t >= d) ? src[t - d] : 0u);
            dst[t] = v;
            __syncthreads();
            unsigned int* tmp = src; src = dst; dst = tmp;
        }
        unsigned int taken = src[t] - myeq;   // equals owned by lower threads
#pragma unroll
        for (int e = 0; e < SEQ / 256; ++e) {
            int idx = t * (SEQ / 256) + e;
            unsigned int u = su[idx];
            if (u > T) gsel[idx] = 1;
            else if (u == T) { if (taken < remaining) gsel[idx] = 1; taken++; }
        }
    }
    __syncthreads();

    for (int k = t; k < SEQ; k += 256) {
        int valid = (amask[b * SEQ + k] != 0) ? 1 : 0;
        int g = gsel[k];
        int r = ((k % RSTRIDE) == 0 && (k / RSTRIDE) < RBUDGET) ? 1 : 0;
        flags[b * SEQ + k] = (unsigned char)(valid | (g << 1) | (r << 2));
    }
}

// One block per batch: analytic connection count from column prefix sums.
// one(i,j) = (j<=i) & vI & vJ & (i-j<128 | hotI | hotJ)
//   hotI:  count = cumV[i]
//   else:  count = (cumV[i] - cumV[i-128]) + cumH[i-128]   (terms 0 if i<128)
__global__ void counts_kernel(const unsigned char* __restrict__ flags,
                              float* __restrict__ out_eff) {
    __shared__ int cumV[SEQ];
    __shared__ int cumH[SEQ];
    __shared__ int tvA[256], tvB[256], thA[256], thB[256];
    __shared__ int red[256];
    int b = blockIdx.x, t = threadIdx.x;
    int base = b * SEQ;

    int lv[16], lh[16];
    int sv = 0, sh = 0;
#pragma unroll
    for (int e = 0; e < 16; ++e) {
        unsigned char f = flags[base + t * 16 + e];
        int v = f & 1;
        int h = v & (((f & 6) != 0) ? 1 : 0);
        sv += v; sh += h;
        lv[e] = sv; lh[e] = sh;
    }
    tvA[t] = sv; thA[t] = sh;
    __syncthreads();
    int* vsrc = tvA; int* vdst = tvB;
    int* hsrc = thA; int* hdst = thB;
    for (int d = 1; d < 256; d <<= 1) {
        int av = vsrc[t] + ((t >= d) ? vsrc[t - d] : 0);
        int ah = hsrc[t] + ((t >= d) ? hsrc[t - d] : 0);
        vdst[t] = av; hdst[t] = ah;
        __syncthreads();
        int* tmp = vsrc; vsrc = vdst; vdst = tmp;
        tmp = hsrc; hsrc = hdst; hdst = tmp;
    }
    int bv = vsrc[t] - sv, bh = hsrc[t] - sh;
#pragma unroll
    for (int e = 0; e < 16; ++e) {
        cumV[t * 16 + e] = lv[e] + bv;
        cumH[t * 16 + e] = lh[e] + bh;
    }
    __syncthreads();

    int cnt = 0;
#pragma unroll
    for (int e = 0; e < 16; ++e) {
        int i = t * 16 + e;
        unsigned char f = flags[base + i];
        int validI = f & 1;
        int hotI = (f & 6) != 0;
        int c;
        if (hotI) c = cumV[i];
        else {
            int w = (i >= LOCALW) ? (cumV[i] - cumV[i - LOCALW]) : cumV[i];
            int g = (i >= LOCALW) ? cumH[i - LOCALW] : 0;
            c = w + g;
        }
        cnt += validI ? c : 0;
    }
    red[t] = cnt;
    __syncthreads();
    for (int s2 = 128; s2; s2 >>= 1) {
        if (t < s2) red[t] += red[t + s2];
        __syncthreads();
    }
    if (t == 0)
        out_eff[b] = (float)red[0] * (1.0f / ((float)SEQ * (float)SEQ));
}

// 4 rows per block, pure compute + nontemporal streaming stores.
// No barrier, no atomic, no LDS -> no per-block store-drain stall.
__global__ void __launch_bounds__(256) mask_kernel(
        const unsigned char* __restrict__ flags,
        float* __restrict__ out) {
    int row0 = blockIdx.x << 2;          // 4 consecutive global rows, same batch
    int b = row0 >> 12;
    int t = threadIdx.x;

    const uchar4* f4 = (const uchar4*)(flags + b * SEQ);
    unsigned int validBits = 0, hotBits = 0;
#pragma unroll
    for (int k = 0; k < 4; ++k) {
        uchar4 f = f4[t + 256 * k];
        unsigned char fa[4] = {f.x, f.y, f.z, f.w};
#pragma unroll
        for (int e = 0; e < 4; ++e) {
            int idx = k * 4 + e;
            validBits |= (unsigned int)(fa[e] & 1u) << idx;
            hotBits   |= (unsigned int)((fa[e] & 6u) ? 1u : 0u) << idx;
        }
    }

    uchar4 fr = *(const uchar4*)(flags + row0);     // row0 % 4 == 0
    unsigned char fra[4] = {fr.x, fr.y, fr.z, fr.w};

#pragma unroll
    for (int r = 0; r < 4; ++r) {
        int i = (row0 + r) & (SEQ - 1);
        int validI = fra[r] & 1;
        int hotI = (fra[r] & 6) != 0;
        nfloat4* outrow4 = (nfloat4*)(out + (size_t)(row0 + r) * SEQ);
#pragma unroll
        for (int k = 0; k < 4; ++k) {
            int j4 = t + 256 * k;
            int j0 = j4 << 2;
            nfloat4 v;
#pragma unroll
            for (int e = 0; e < 4; ++e) {
                int idx = k * 4 + e;
                int j = j0 + e;
                int one = (j <= i) & validI & (int)((validBits >> idx) & 1u)
                        & (((i - j) < LOCALW) | hotI | (int)((hotBits >> idx) & 1u));
                v[e] = one ? 1.0f : 0.0f;
            }
            __builtin_nontemporal_store(v, outrow4 + j4);
        }
    }
}

// selected: local.any(axis=0) is all-True (diagonal), so selected == True
__global__ void finalize_kernel(float* __restrict__ out_selected) {
    int idx = blockIdx.x * 256 + threadIdx.x;
    if (idx < BATCH * SEQ) out_selected[idx] = 1.0f;
}

extern "C" void kernel_launch(void* const* d_in, const int* in_sizes, int n_in,
                              void* d_out, int out_size, void* d_ws, size_t ws_size,
                              hipStream_t stream) {
    const float* hs    = (const float*)d_in[0];   // [B,S,D] f32
    const int*   amask = (const int*)d_in[1];     // [B,S] i32
    const float* W     = (const float*)d_in[2];   // [1,D] f32

    char* ws = (char*)d_ws;
    float*         scores = (float*)(ws + WS_SCORES_OFF);
    unsigned char* flags  = (unsigned char*)(ws + WS_FLAGS_OFF);

    float* out_sparse   = (float*)d_out;                          // B*S*S
    float* out_selected = out_sparse + (size_t)BATCH * SEQ * SEQ; // B*S
    float* out_eff      = out_selected + BATCH * SEQ;             // B

    scores_kernel<<<BATCH * SEQ / 4, 256, 0, stream>>>(hs, amask, W, scores);
    topk_flags_kernel<<<BATCH, 256, 0, stream>>>(scores, amask, flags);
    counts_kernel<<<BATCH, 256, 0, stream>>>(flags, out_eff);
    mask_kernel<<<BATCH * SEQ / 4, 256, 0, stream>>>(flags, out_sparse);
    finalize_kernel<<<(BATCH * SEQ + 255) / 256, 256, 0, stream>>>(out_selected);
}